// Round 1
// baseline (231.642 us; speedup 1.0000x reference)
//
#include <hip/hip_runtime.h>

// Problem constants (match reference)
#define Dd 16
#define Zd 64
#define Yd 128
#define Xd 128
#define Cd 2

__device__ __forceinline__ void spline_w(float coord, int size, int* idx4, float* w) {
    int i0 = (int)coord;                       // trunc toward zero; coords >= 0
    float s = coord - (float)i0;
    s = fminf(fmaxf(s, 0.0f), 1.0f);
#pragma unroll
    for (int j = 0; j < 4; ++j) {
        int k = i0 - 1 + j;
        idx4[j] = min(max(k, 0), size - 1);
    }
    float s2 = s * s, s3 = s2 * s;
    // powers @ (HERMITE @ CR) = Catmull-Rom weights
    w[0] = -0.5f * s3 + s2 - 0.5f * s;
    w[1] =  1.5f * s3 - 2.5f * s2 + 1.0f;
    w[2] = -1.5f * s3 + 2.0f * s2 + 0.5f * s;
    w[3] =  0.5f * s3 - 0.5f * s2;
}

// depths = arange(1, D+1): searchsorted + lerp collapses to depth_coord = depth - 1
__device__ __forceinline__ void depth_w(float depth, int* id4, float* wd) {
    float dc = depth - 1.0f;
    spline_w(dc, Dd, id4, wd);
}

// Kernel A: contract depth dim. W[z][y][x][c] = sum_j wd[j] * knots[id[j]][z][y][x][c]
__global__ void depth_contract_kernel(const float* __restrict__ knots,
                                      const float* __restrict__ depth_p,
                                      float4* __restrict__ Wv) {
    const int nv = Zd * Yd * Xd * Cd / 4;      // 524288 float4
    int t = blockIdx.x * blockDim.x + threadIdx.x;
    if (t >= nv) return;

    int id[4]; float wd[4];
    depth_w(depth_p[0], id, wd);

    const float4* kv = (const float4*)knots;
    const size_t slice = (size_t)Zd * Yd * Xd * Cd / 4;   // float4 per depth slice
    float4 a = kv[(size_t)id[0] * slice + t];
    float4 b = kv[(size_t)id[1] * slice + t];
    float4 c = kv[(size_t)id[2] * slice + t];
    float4 d = kv[(size_t)id[3] * slice + t];
    float4 r;
    r.x = wd[0] * a.x + wd[1] * b.x + wd[2] * c.x + wd[3] * d.x;
    r.y = wd[0] * a.y + wd[1] * b.y + wd[2] * c.y + wd[3] * d.y;
    r.z = wd[0] * a.z + wd[1] * b.z + wd[2] * c.z + wd[3] * d.z;
    r.w = wd[0] * a.w + wd[1] * b.w + wd[2] * c.w + wd[3] * d.w;
    Wv[t] = r;
}

// Kernel B: per-point 3D gather over the depth-contracted volume.
__global__ void gather_eval_kernel(const float* __restrict__ idx,
                                   const float* __restrict__ W,
                                   float* __restrict__ out, int n_pts) {
    int n = blockIdx.x * blockDim.x + threadIdx.x;
    if (n >= n_pts) return;

    float zc = idx[n * 3 + 0];
    float yc = idx[n * 3 + 1];
    float xc = idx[n * 3 + 2];

    int iz[4], iy[4], ix[4];
    float wz[4], wy[4], wx[4];
    spline_w(zc, Zd, iz, wz);
    spline_w(yc, Yd, iy, wy);
    spline_w(xc, Xd, ix, wx);

    float acc0 = 0.0f, acc1 = 0.0f;
#pragma unroll
    for (int a = 0; a < 4; ++a) {
#pragma unroll
        for (int b = 0; b < 4; ++b) {
            const float2* row = (const float2*)(W + ((size_t)(iz[a] * Yd + iy[b]) * Xd) * Cd);
            float r0 = 0.0f, r1 = 0.0f;
#pragma unroll
            for (int q = 0; q < 4; ++q) {
                float2 v = row[ix[q]];          // (c0,c1) at one x — 8B contiguous
                r0 = fmaf(wx[q], v.x, r0);
                r1 = fmaf(wx[q], v.y, r1);
            }
            float wzy = wz[a] * wy[b];
            acc0 = fmaf(wzy, r0, acc0);
            acc1 = fmaf(wzy, r1, acc1);
        }
    }
    out[n * 2 + 0] = acc0;
    out[n * 2 + 1] = acc1;
}

// Fallback: fully fused (used only if d_ws can't hold the 8 MB contracted volume).
__global__ void fused_kernel(const float* __restrict__ idx,
                             const float* __restrict__ knots,
                             const float* __restrict__ depth_p,
                             float* __restrict__ out, int n_pts) {
    int n = blockIdx.x * blockDim.x + threadIdx.x;
    if (n >= n_pts) return;

    int id[4]; float wd[4];
    depth_w(depth_p[0], id, wd);

    float zc = idx[n * 3 + 0];
    float yc = idx[n * 3 + 1];
    float xc = idx[n * 3 + 2];

    int iz[4], iy[4], ix[4];
    float wz[4], wy[4], wx[4];
    spline_w(zc, Zd, iz, wz);
    spline_w(yc, Yd, iy, wy);
    spline_w(xc, Xd, ix, wx);

    float acc0 = 0.0f, acc1 = 0.0f;
    for (int dd = 0; dd < 4; ++dd) {
        const float* base = knots + (size_t)id[dd] * Zd * Yd * Xd * Cd;
        float d0 = 0.0f, d1 = 0.0f;
#pragma unroll
        for (int a = 0; a < 4; ++a) {
#pragma unroll
            for (int b = 0; b < 4; ++b) {
                const float2* row = (const float2*)(base + ((size_t)(iz[a] * Yd + iy[b]) * Xd) * Cd);
                float r0 = 0.0f, r1 = 0.0f;
#pragma unroll
                for (int q = 0; q < 4; ++q) {
                    float2 v = row[ix[q]];
                    r0 = fmaf(wx[q], v.x, r0);
                    r1 = fmaf(wx[q], v.y, r1);
                }
                float wzy = wz[a] * wy[b];
                d0 = fmaf(wzy, r0, d0);
                d1 = fmaf(wzy, r1, d1);
            }
        }
        acc0 = fmaf(wd[dd], d0, acc0);
        acc1 = fmaf(wd[dd], d1, acc1);
    }
    out[n * 2 + 0] = acc0;
    out[n * 2 + 1] = acc1;
}

extern "C" void kernel_launch(void* const* d_in, const int* in_sizes, int n_in,
                              void* d_out, int out_size, void* d_ws, size_t ws_size,
                              hipStream_t stream) {
    const float* idx   = (const float*)d_in[0];   // [N,3] f32
    const float* knots = (const float*)d_in[1];   // [16,64,128,128,2] f32
    const float* depth = (const float*)d_in[2];   // scalar f32
    float* out = (float*)d_out;                   // [N,2] f32
    const int n_pts = in_sizes[0] / 3;

    const size_t need = (size_t)Zd * Yd * Xd * Cd * sizeof(float);  // 8 MB
    if (ws_size >= need) {
        float* W = (float*)d_ws;
        const int nv = Zd * Yd * Xd * Cd / 4;
        depth_contract_kernel<<<(nv + 255) / 256, 256, 0, stream>>>(knots, depth, (float4*)W);
        gather_eval_kernel<<<(n_pts + 255) / 256, 256, 0, stream>>>(idx, W, out, n_pts);
    } else {
        fused_kernel<<<(n_pts + 255) / 256, 256, 0, stream>>>(idx, knots, depth, out, n_pts);
    }
}

// Round 2
// 213.858 us; speedup vs baseline: 1.0832x; 1.0832x over previous
//
#include <hip/hip_runtime.h>

// Problem constants (match reference)
#define Dd 16
#define Zd 64
#define Yd 128
#define Xd 128
#define Cd 2

__device__ __forceinline__ void spline_w(float coord, int size, int* idx4, float* w) {
    int i0 = (int)coord;                       // trunc toward zero; coords >= 0
    float s = coord - (float)i0;
    s = fminf(fmaxf(s, 0.0f), 1.0f);
#pragma unroll
    for (int j = 0; j < 4; ++j) {
        int k = i0 - 1 + j;
        idx4[j] = min(max(k, 0), size - 1);
    }
    float s2 = s * s, s3 = s2 * s;
    // powers @ (HERMITE @ CR) = Catmull-Rom weights
    w[0] = -0.5f * s3 + s2 - 0.5f * s;
    w[1] =  1.5f * s3 - 2.5f * s2 + 1.0f;
    w[2] = -1.5f * s3 + 2.0f * s2 + 0.5f * s;
    w[3] =  0.5f * s3 - 0.5f * s2;
}

// depths = arange(1, D+1): searchsorted + lerp collapses to depth_coord = depth - 1
__device__ __forceinline__ void depth_w(float depth, int* id4, float* wd) {
    float dc = depth - 1.0f;
    spline_w(dc, Dd, id4, wd);
}

// Kernel A: contract depth dim. W[z][y][x][c] = sum_j wd[j] * knots[id[j]][z][y][x][c]
__global__ void depth_contract_kernel(const float* __restrict__ knots,
                                      const float* __restrict__ depth_p,
                                      float4* __restrict__ Wv) {
    const int nv = Zd * Yd * Xd * Cd / 4;      // 524288 float4
    int t = blockIdx.x * blockDim.x + threadIdx.x;
    if (t >= nv) return;

    int id[4]; float wd[4];
    depth_w(depth_p[0], id, wd);

    const float4* kv = (const float4*)knots;
    const size_t slice = (size_t)Zd * Yd * Xd * Cd / 4;   // float4 per depth slice
    float4 a = kv[(size_t)id[0] * slice + t];
    float4 b = kv[(size_t)id[1] * slice + t];
    float4 c = kv[(size_t)id[2] * slice + t];
    float4 d = kv[(size_t)id[3] * slice + t];
    float4 r;
    r.x = wd[0] * a.x + wd[1] * b.x + wd[2] * c.x + wd[3] * d.x;
    r.y = wd[0] * a.y + wd[1] * b.y + wd[2] * c.y + wd[3] * d.y;
    r.z = wd[0] * a.z + wd[1] * b.z + wd[2] * c.z + wd[3] * d.z;
    r.w = wd[0] * a.w + wd[1] * b.w + wd[2] * c.w + wd[3] * d.w;
    Wv[t] = r;
}

// Kernel B: 4 lanes per point. Lane q in [0,4) owns x-offset q, so each of the
// 16 row-load instructions has quads of lanes covering contiguous 32B segments
// (coalesced), instead of 64 fully-scattered 8B lanes. 16 independent loads per
// thread -> deep MLP; quad shfl_xor reduce at the end.
__global__ void gather_eval_kernel(const float* __restrict__ idx,
                                   const float* __restrict__ W,
                                   float* __restrict__ out, int n_pts) {
    int t = blockIdx.x * blockDim.x + threadIdx.x;
    int n = t >> 2;            // point index
    int q = t & 3;             // x offset within the 4-tap stencil
    if (n >= n_pts) return;

    float zc = idx[n * 3 + 0];
    float yc = idx[n * 3 + 1];
    float xc = idx[n * 3 + 2];

    int iz[4], iy[4], ix[4];
    float wz[4], wy[4], wx[4];
    spline_w(zc, Zd, iz, wz);
    spline_w(yc, Yd, iy, wy);
    spline_w(xc, Xd, ix, wx);

    const int ixq = ix[q];
    const float wxq = wx[q];

    // Row base offsets (in float2 units): (iz[a]*Yd + iy[b])*Xd + ixq
    const float2* __restrict__ Wv = (const float2*)W;

    float r0 = 0.0f, r1 = 0.0f;
#pragma unroll
    for (int a = 0; a < 4; ++a) {
        const int zoff = iz[a] * (Yd * Xd);
#pragma unroll
        for (int b = 0; b < 4; ++b) {
            float2 v = Wv[(size_t)(zoff + iy[b] * Xd + ixq)];
            float wzy = wz[a] * wy[b];
            r0 = fmaf(wzy, v.x, r0);
            r1 = fmaf(wzy, v.y, r1);
        }
    }
    r0 *= wxq;
    r1 *= wxq;

    // Reduce across the quad (lanes q=0..3 of this point)
    r0 += __shfl_xor(r0, 1);
    r0 += __shfl_xor(r0, 2);
    r1 += __shfl_xor(r1, 1);
    r1 += __shfl_xor(r1, 2);

    if (q == 0) {
        float2* ov = (float2*)out;
        float2 o; o.x = r0; o.y = r1;
        ov[n] = o;
    }
}

// Fallback: fully fused (used only if d_ws can't hold the 8 MB contracted volume).
__global__ void fused_kernel(const float* __restrict__ idx,
                             const float* __restrict__ knots,
                             const float* __restrict__ depth_p,
                             float* __restrict__ out, int n_pts) {
    int n = blockIdx.x * blockDim.x + threadIdx.x;
    if (n >= n_pts) return;

    int id[4]; float wd[4];
    depth_w(depth_p[0], id, wd);

    float zc = idx[n * 3 + 0];
    float yc = idx[n * 3 + 1];
    float xc = idx[n * 3 + 2];

    int iz[4], iy[4], ix[4];
    float wz[4], wy[4], wx[4];
    spline_w(zc, Zd, iz, wz);
    spline_w(yc, Yd, iy, wy);
    spline_w(xc, Xd, ix, wx);

    float acc0 = 0.0f, acc1 = 0.0f;
    for (int dd = 0; dd < 4; ++dd) {
        const float* base = knots + (size_t)id[dd] * Zd * Yd * Xd * Cd;
        float d0 = 0.0f, d1 = 0.0f;
#pragma unroll
        for (int a = 0; a < 4; ++a) {
#pragma unroll
            for (int b = 0; b < 4; ++b) {
                const float2* row = (const float2*)(base + ((size_t)(iz[a] * Yd + iy[b]) * Xd) * Cd);
                float r0 = 0.0f, r1 = 0.0f;
#pragma unroll
                for (int qq = 0; qq < 4; ++qq) {
                    float2 v = row[ix[qq]];
                    r0 = fmaf(wx[qq], v.x, r0);
                    r1 = fmaf(wx[qq], v.y, r1);
                }
                float wzy = wz[a] * wy[b];
                d0 = fmaf(wzy, r0, d0);
                d1 = fmaf(wzy, r1, d1);
            }
        }
        acc0 = fmaf(wd[dd], d0, acc0);
        acc1 = fmaf(wd[dd], d1, acc1);
    }
    out[n * 2 + 0] = acc0;
    out[n * 2 + 1] = acc1;
}

extern "C" void kernel_launch(void* const* d_in, const int* in_sizes, int n_in,
                              void* d_out, int out_size, void* d_ws, size_t ws_size,
                              hipStream_t stream) {
    const float* idx   = (const float*)d_in[0];   // [N,3] f32
    const float* knots = (const float*)d_in[1];   // [16,64,128,128,2] f32
    const float* depth = (const float*)d_in[2];   // scalar f32
    float* out = (float*)d_out;                   // [N,2] f32
    const int n_pts = in_sizes[0] / 3;

    const size_t need = (size_t)Zd * Yd * Xd * Cd * sizeof(float);  // 8 MB
    if (ws_size >= need) {
        float* W = (float*)d_ws;
        const int nv = Zd * Yd * Xd * Cd / 4;
        depth_contract_kernel<<<(nv + 255) / 256, 256, 0, stream>>>(knots, depth, (float4*)W);
        const int nthreads = n_pts * 4;
        gather_eval_kernel<<<(nthreads + 255) / 256, 256, 0, stream>>>(idx, W, out, n_pts);
    } else {
        fused_kernel<<<(n_pts + 255) / 256, 256, 0, stream>>>(idx, knots, depth, out, n_pts);
    }
}